// Round 13
// baseline (271.704 us; speedup 1.0000x reference)
//
#include <hip/hip_runtime.h>
#include <hip/hip_bf16.h>
#include <stdint.h>

#define B_ 4
#define C_ 384
#define H_ 128
#define W_ 128
#define L_ (H_*W_)      // 16384
#define NH 8
#define DH 48           // C_/NH
#define SPLIT 8

typedef __attribute__((ext_vector_type(8))) short bf16x8;
typedef __attribute__((ext_vector_type(4))) float f32x4;
typedef unsigned short u16;
typedef unsigned int u32;

__device__ __forceinline__ float bf2f(u16 v){
  union { float f; u32 u; } x; x.u = ((u32)v) << 16; return x.f;
}
__device__ __forceinline__ u16 f2bf(float f){
  __hip_bfloat16 h = __float2bfloat16(f);
  return *reinterpret_cast<u16*>(&h);
}

#define GLOAD_LDS16(g, l) \
  __builtin_amdgcn_global_load_lds((const __attribute__((address_space(1))) u32*)(g), \
                                   (__attribute__((address_space(3))) u32*)(l), 16, 0, 0)

// ---------------- K1: fused prep: LN1 (blocks 0..1023) + weight convert (1024..2751) ----------------
__global__ __launch_bounds__(256) void k_prep(const float* __restrict__ x,
                                              const float* __restrict__ w,
                                              const float* __restrict__ b,
                                              u16* __restrict__ xt,
                                              const float* __restrict__ wq,
                                              const float* __restrict__ wk,
                                              const float* __restrict__ wv,
                                              u16* __restrict__ wc){
  if ((int)blockIdx.x >= 1024){
    int i = ((int)blockIdx.x - 1024) * 256 + threadIdx.x;
    if (i < 3*C_*C_){
      int m = i / C_;
      int c = i - m*C_;
      const float* src = (m < C_) ? wq : (m < 2*C_) ? wk : wv;
      int mm = (m >= 2*C_) ? m - 2*C_ : (m >= C_) ? m - C_ : m;
      wc[i] = f2bf(src[mm*C_ + c]);
    }
    return;
  }
  const int tid = threadIdx.x;
  const int bb = blockIdx.x >> 8;          // 256 blocks per batch
  const int l0 = (blockIdx.x & 255) << 6;  // 64-pixel tile
  const int pg = tid >> 4;                 // 0..15, pixels pg*4..pg*4+3
  const int cg = tid & 15;                 // 0..15, channels cg*24..cg*24+23
  const int c0 = cg * 24;
  const float* xp = x + (size_t)bb*C_*L_ + (size_t)c0*L_ + l0 + pg*4;

  f32x4 vals[24];
  #pragma unroll
  for (int ci = 0; ci < 24; ++ci)
    vals[ci] = *reinterpret_cast<const f32x4*>(xp + (size_t)ci*L_);

  f32x4 s = {0.f,0.f,0.f,0.f}, s2 = {0.f,0.f,0.f,0.f};
  #pragma unroll
  for (int ci = 0; ci < 24; ++ci){ s += vals[ci]; s2 += vals[ci]*vals[ci]; }
  #pragma unroll
  for (int m = 1; m < 16; m <<= 1){
    #pragma unroll
    for (int r = 0; r < 4; ++r){
      s[r]  += __shfl_xor(s[r],  m);
      s2[r] += __shfl_xor(s2[r], m);
    }
  }
  f32x4 mu, rstd;
  #pragma unroll
  for (int r = 0; r < 4; ++r){
    mu[r]   = s[r] * (1.f/C_);
    rstd[r] = rsqrtf(s2[r]*(1.f/C_) - mu[r]*mu[r] + 1e-5f);
  }

  u16* dst = xt + ((size_t)bb*L_ + l0 + pg*4)*C_ + c0;
  #pragma unroll
  for (int j = 0; j < 3; ++j){
    f32x4 w0 = *reinterpret_cast<const f32x4*>(w + c0 + j*8);
    f32x4 w1 = *reinterpret_cast<const f32x4*>(w + c0 + j*8 + 4);
    f32x4 b0 = *reinterpret_cast<const f32x4*>(b + c0 + j*8);
    f32x4 b1 = *reinterpret_cast<const f32x4*>(b + c0 + j*8 + 4);
    #pragma unroll
    for (int pp = 0; pp < 4; ++pp){
      uint4 pk;
      u16* tp = reinterpret_cast<u16*>(&pk);
      #pragma unroll
      for (int e = 0; e < 4; ++e)
        tp[e]   = f2bf((vals[j*8+e][pp]   - mu[pp]) * rstd[pp] * w0[e] + b0[e]);
      #pragma unroll
      for (int e = 0; e < 4; ++e)
        tp[4+e] = f2bf((vals[j*8+4+e][pp] - mu[pp]) * rstd[pp] * w1[e] + b1[e]);
      *reinterpret_cast<uint4*>(dst + (size_t)pp*C_ + j*8) = pk;
    }
  }
}

// ---------------- K2: GEMM qkv = Wc[1152x384] * xt^T -> [3][B][C][L] bf16 ----------------
// Phase-split schedule (T3-lite + T4 + T5 on the proven R8 machinery):
// 128x256 tile, 512 thr / 8 waves, BK=64, 6 K-tiles. Triple-buffered LDS slots
// (144 KB, 1 block/CU), stage tile t+2 after tile-t barrier, counted vmcnt(6).
// Per tile: 2 compute phases (k-half), mid-tile role-split barrier, setprio(1)
// around each 16-MFMA cluster. 8-chunk/row swizzle: store global chunk
// q^(row&7) at linear chunk q; read chunk (kh*4+kqi)^(fr&7) -> conflict-free.
#define SLOTA (128*64)   // u16 per A slot (16 KB)
#define SLOTB (256*64)   // u16 per B slot (32 KB)
__global__ __launch_bounds__(512) void k_gemm(const u16* __restrict__ Wc,
                                              const u16* __restrict__ Xt,
                                              u16* __restrict__ qkv){
  __shared__ u16 As[3*SLOTA];   // 48 KB
  __shared__ u16 Bs[3*SLOTB];   // 96 KB
  const int tid = threadIdx.x;
  const int wg = (int)blockIdx.x;
  const int lin = (wg & 7) * 288 + (wg >> 3);
  const int bm = lin % 9;
  const int bn = lin / 9;
  const int m0 = bm * 128;
  const int n0 = bn * 256;
  const int w = tid >> 6, lane = tid & 63;
  const int wm = (w >> 2) * 64, wn = (w & 3) * 64;
  const int fr = lane & 15, kqi = lane >> 4;

  f32x4 acc[4][4] = {};

#define STAGE(slot, k0) do { \
    _Pragma("unroll") \
    for (int a_ = 0; a_ < 2; ++a_){ \
      int idx_ = a_*512 + tid; \
      int row_ = idx_ >> 3, q_ = idx_ & 7; \
      int qs_ = q_ ^ (row_ & 7); \
      GLOAD_LDS16(Wc + (size_t)(m0+row_)*384 + (k0) + qs_*8, As + (slot)*SLOTA + idx_*8); \
    } \
    _Pragma("unroll") \
    for (int b_ = 0; b_ < 4; ++b_){ \
      int idx_ = b_*512 + tid; \
      int row_ = idx_ >> 3, q_ = idx_ & 7; \
      int qs_ = q_ ^ (row_ & 7); \
      GLOAD_LDS16(Xt + (size_t)(n0+row_)*384 + (k0) + qs_*8, Bs + (slot)*SLOTB + idx_*8); \
    } } while(0)

  STAGE(0, 0);
  STAGE(1, 64);

  #pragma unroll
  for (int t = 0; t < 6; ++t){
    const int cur = t % 3;
    __builtin_amdgcn_sched_barrier(0);
    if (t < 5) asm volatile("s_waitcnt vmcnt(6)" ::: "memory");
    else       asm volatile("s_waitcnt vmcnt(0)" ::: "memory");
    __builtin_amdgcn_sched_barrier(0);
    __builtin_amdgcn_s_barrier();
    __builtin_amdgcn_sched_barrier(0);
    if (t + 2 < 6) STAGE((t+2)%3, (t+2)*64);
    __builtin_amdgcn_sched_barrier(0);

    const u16* Ab = As + cur*SLOTA;
    const u16* Bb = Bs + cur*SLOTB;
    #pragma unroll
    for (int kh = 0; kh < 2; ++kh){
      bf16x8 af[4], bfm[4];
      const int ch = ((kh*4 + kqi) ^ (fr & 7)) * 8;
      #pragma unroll
      for (int i = 0; i < 4; ++i)
        af[i] = *reinterpret_cast<const bf16x8*>(Ab + (wm + i*16 + fr)*64 + ch);
      #pragma unroll
      for (int j = 0; j < 4; ++j)
        bfm[j] = *reinterpret_cast<const bf16x8*>(Bb + (wn + j*16 + fr)*64 + ch);
      __builtin_amdgcn_s_setprio(1);
      #pragma unroll
      for (int i = 0; i < 4; ++i)
        #pragma unroll
        for (int j = 0; j < 4; ++j)
          acc[i][j] = __builtin_amdgcn_mfma_f32_16x16x32_bf16(af[i], bfm[j], acc[i][j], 0, 0, 0);
      __builtin_amdgcn_s_setprio(0);
      if (kh == 0){
        __builtin_amdgcn_sched_barrier(0);
        __builtin_amdgcn_s_barrier();
        __builtin_amdgcn_sched_barrier(0);
      }
    }
  }
#undef STAGE

  #pragma unroll
  for (int i = 0; i < 4; ++i){
    int mbase = m0 + wm + i*16 + (lane >> 4) * 4;
    #pragma unroll
    for (int j = 0; j < 4; ++j){
      int n = n0 + wn + j*16 + fr;
      int bb = n >> 14, l = n & (L_-1);
      #pragma unroll
      for (int r = 0; r < 4; ++r){
        int m = mbase + r;
        int proj = (m >= 2*C_) ? 2 : (m >= C_) ? 1 : 0;
        int c = m - proj*C_;
        qkv[(((size_t)proj*B_ + bb)*C_ + c)*L_ + l] = f2bf(acc[i][j][r]);
      }
    }
  }
}

// ---------------- K3: depthwise 3x3 in-place + per-channel sumsq for q,k ----------------
__global__ __launch_bounds__(256) void k_dwconv(u16* __restrict__ qkv,
                                                const float* __restrict__ dwq,
                                                const float* __restrict__ dwk,
                                                const float* __restrict__ dwv,
                                                float* __restrict__ sumsq){
  __shared__ u16 pl[128*128];
  int pid = blockIdx.x;                  // t*B*C + b*C + c
  int t = pid / (B_*C_);
  int bc = pid - t*(B_*C_);
  int c = bc % C_;
  const float* dw = ((t == 0) ? dwq : (t == 1) ? dwk : dwv) + c*9;
  u16* plane = qkv + ((size_t)t*B_*C_ + bc) * L_;
  int tid = threadIdx.x;
  #pragma unroll
  for (int i = 0; i < 8; ++i){
    int idx = i*256 + tid;
    GLOAD_LDS16(plane + idx*8, pl + idx*8);
  }
  float wgt[9];
  #pragma unroll
  for (int i = 0; i < 9; ++i) wgt[i] = dw[i];
  asm volatile("s_waitcnt vmcnt(0)" ::: "memory");
  __syncthreads();

  const int tx = tid & 15;           // tile col: pixels tx*8..tx*8+7
  const int ty = tid >> 4;           // tile row: rows ty*8..ty*8+7
  const int lane = tid & 63;
  const int y0 = ty*8;

  float rv[3][8], rl[3], rr_[3];
  float ss = 0.f;

  #pragma unroll
  for (int i = 0; i < 10; ++i){
    const int sl = i % 3;
    int r = y0 - 1 + i;
    int rc = (r < 0) ? 0 : (r > 127 ? 127 : r);
    uint4 pk = *reinterpret_cast<const uint4*>(pl + rc*128 + tx*8);
    const u16* e = reinterpret_cast<const u16*>(&pk);
    bool oob = (r < 0) || (r > 127);
    #pragma unroll
    for (int k = 0; k < 8; ++k)
      rv[sl][k] = oob ? 0.f : bf2f(e[k]);
    float lft = __shfl(rv[sl][7], lane - 1);
    float rgt = __shfl(rv[sl][0], lane + 1);
    rl[sl]  = (tx == 0)  ? 0.f : lft;
    rr_[sl] = (tx == 15) ? 0.f : rgt;

    if (i >= 2){
      const int sa = (i-2) % 3, sb = (i-1) % 3, sc = i % 3;
      const int y = i - 2;
      float o[8];
      #pragma unroll
      for (int xx = 0; xx < 8; ++xx){
        float am1 = (xx == 0) ? rl[sa]  : rv[sa][xx-1];
        float ap1 = (xx == 7) ? rr_[sa] : rv[sa][xx+1];
        float bm1 = (xx == 0) ? rl[sb]  : rv[sb][xx-1];
        float bp1 = (xx == 7) ? rr_[sb] : rv[sb][xx+1];
        float cm1 = (xx == 0) ? rl[sc]  : rv[sc][xx-1];
        float cp1 = (xx == 7) ? rr_[sc] : rv[sc][xx+1];
        float a = wgt[0]*am1 + wgt[1]*rv[sa][xx] + wgt[2]*ap1
                + wgt[3]*bm1 + wgt[4]*rv[sb][xx] + wgt[5]*bp1
                + wgt[6]*cm1 + wgt[7]*rv[sc][xx] + wgt[8]*cp1;
        o[xx] = a;
        ss += a * a;
      }
      uint4 st;
      u16* sp = reinterpret_cast<u16*>(&st);
      #pragma unroll
      for (int xx = 0; xx < 8; ++xx) sp[xx] = f2bf(o[xx]);
      *reinterpret_cast<uint4*>(plane + (y0 + y)*128 + tx*8) = st;
    }
  }

  if (t < 2){
    #pragma unroll
    for (int off = 32; off > 0; off >>= 1) ss += __shfl_down(ss, off);
    __shared__ float red[4];
    if ((tid & 63) == 0) red[tid >> 6] = ss;
    __syncthreads();
    if (tid == 0) sumsq[t*(B_*C_) + bc] = red[0] + red[1] + red[2] + red[3];
  }
}

// ---------------- K4: attention logits (split-K over L), S_part[s][b][n][48][48] ----------------
__global__ __launch_bounds__(512) void k_qk(const u16* __restrict__ qkv,
                                            float* __restrict__ Spart){
  int gid = blockIdx.x;                 // (s*B + b)*NH + n
  int s = gid / (B_*NH);
  int bn = gid - s*(B_*NH);
  int b = bn / NH, n = bn - b*NH;
  const u16* qb = qkv + ((size_t)b*C_ + n*DH) * L_;
  const u16* kb = qkv + ((size_t)B_*C_ + (size_t)b*C_ + n*DH) * L_;
  int tid = threadIdx.x, w = tid >> 6, lane = tid & 63;
  int fr = lane & 15, kq = (lane >> 4) * 8;
  int l0 = s * (L_/SPLIT) + w * (L_/SPLIT/8);     // 2048/block, 256/wave
  f32x4 acc[3][3] = {};
  #pragma unroll
  for (int kk = 0; kk < (L_/SPLIT/8); kk += 32){
    int koff = l0 + kk + kq;
    bf16x8 af[3], bfm[3];
    #pragma unroll
    for (int i = 0; i < 3; ++i) af[i]  = *reinterpret_cast<const bf16x8*>(qb + (size_t)(i*16+fr)*L_ + koff);
    #pragma unroll
    for (int j = 0; j < 3; ++j) bfm[j] = *reinterpret_cast<const bf16x8*>(kb + (size_t)(j*16+fr)*L_ + koff);
    #pragma unroll
    for (int i = 0; i < 3; ++i)
      #pragma unroll
      for (int j = 0; j < 3; ++j)
        acc[i][j] = __builtin_amdgcn_mfma_f32_16x16x32_bf16(af[i], bfm[j], acc[i][j], 0, 0, 0);
  }
  __shared__ float red[8*2304];        // 73.7 KB, one 48x48 slice per wave
  float* rw = red + w*2304;
  #pragma unroll
  for (int i = 0; i < 3; ++i)
    #pragma unroll
    for (int j = 0; j < 3; ++j)
      #pragma unroll
      for (int r = 0; r < 4; ++r){
        int row = i*16 + (lane >> 4)*4 + r;
        int col = j*16 + fr;
        rw[row*48 + col] = acc[i][j][r];
      }
  __syncthreads();
  float* dst = Spart + ((size_t)gid) * 2304;
  for (int idx = tid; idx < 2304; idx += 512){
    float a = 0.f;
    #pragma unroll
    for (int ww = 0; ww < 8; ++ww) a += red[ww*2304 + idx];
    dst[idx] = a;
  }
}

// ---------------- K5: reduce split-K, fold L2 norms + scale, softmax -> bf16 hi|lo [d][96] ----------------
__global__ void k_softmax(const float* __restrict__ Spart,
                          const float* __restrict__ sumsq,
                          const float* __restrict__ scale,
                          u16* __restrict__ attn96){
  int bn = blockIdx.x;                  // b*NH + n
  int b = bn / NH, n = bn - b*NH;
  int i = threadIdx.x;
  if (i >= DH) return;
  const float* sq = sumsq + (size_t)b*C_ + n*DH;
  const float* sk = sumsq + (size_t)B_*C_ + (size_t)b*C_ + n*DH;
  float nq = fmaxf(sqrtf(sq[i]), 1e-12f);
  float sc = scale[n];
  float row[48];
  #pragma unroll
  for (int j = 0; j < DH; ++j){
    float acc = 0.f;
    #pragma unroll
    for (int s = 0; s < SPLIT; ++s)
      acc += Spart[((size_t)(s*(B_*NH) + bn))*2304 + i*48 + j];
    float nk = fmaxf(sqrtf(sk[j]), 1e-12f);
    row[j] = acc / (nq * nk) * sc;
  }
  float m = row[0];
  #pragma unroll
  for (int j = 1; j < DH; ++j) m = fmaxf(m, row[j]);
  float sum = 0.f;
  #pragma unroll
  for (int j = 0; j < DH; ++j){ row[j] = __expf(row[j] - m); sum += row[j]; }
  float inv = 1.f / sum;
  u16* dst = attn96 + ((size_t)bn)*DH*96 + i*96;     // row d=i: hi[0..48) | lo[48..96)
  #pragma unroll
  for (int j = 0; j < DH; ++j){
    float a = row[j] * inv;
    u16 hi = f2bf(a);
    float lo = a - bf2f(hi);
    dst[j]      = hi;
    dst[48 + j] = f2bf(lo);
  }
}

// ---------------- K6: out = attn @ v via MFMA (hi+lo split-K=96), fused LayerNorm ----------------
#define VT_STRIDE 784
__device__ __forceinline__ int vt_off(int p, int ch){
  return p*VT_STRIDE + ((p>>3)<<4) + 2*ch;
}
__global__ __launch_bounds__(256) void k_av_ln2(const u16* __restrict__ qkv,
                                                const u16* __restrict__ attn96,
                                                const float* __restrict__ w2,
                                                const float* __restrict__ b2,
                                                float* __restrict__ out){
  __shared__ u16 vt[(64*VT_STRIDE + 8*16)/2];     // 50304 B
  char* vtb = reinterpret_cast<char*>(vt);
  const int tid = threadIdx.x;
  const int bb = blockIdx.x >> 8;        // 256 tiles per batch
  const int l0 = (blockIdx.x & 255) << 6;
  const u16* vg = qkv + ((size_t)2*B_*C_ + (size_t)bb*C_)*L_ + l0;

  // stage v[c][l0..l0+63] -> vt[p][c] (transposed): channel-pairs, u32 writes
  #pragma unroll
  for (int it = 0; it < 6; ++it){
    int idx = it*256 + tid;            // 0..1535
    int cp = idx >> 3, g = idx & 7;    // cp: channel pair 0..191, g: pixel group
    int c = cp*2;
    uint4 p0 = *reinterpret_cast<const uint4*>(vg + (size_t)c*L_ + g*8);
    uint4 p1 = *reinterpret_cast<const uint4*>(vg + (size_t)(c+1)*L_ + g*8);
    const u16* e0 = reinterpret_cast<const u16*>(&p0);
    const u16* e1 = reinterpret_cast<const u16*>(&p1);
    #pragma unroll
    for (int j = 0; j < 8; ++j){
      int p = g*8 + j;
      u32 packed = ((u32)e0[j]) | (((u32)e1[j]) << 16);
      *reinterpret_cast<u32*>(vtb + vt_off(p, c)) = packed;
    }
  }
  __syncthreads();

  const int w = tid >> 6, lane = tid & 63;
  const int fr = lane & 15, kq = (lane >> 4) * 8;
  const int prow = w*16;
  f32x4 acc[24];
  #pragma unroll
  for (int j = 0; j < 24; ++j) acc[j] = (f32x4){0.f,0.f,0.f,0.f};

  const u16* ab = attn96 + ((size_t)bb*NH)*DH*96;
  #pragma unroll
  for (int n = 0; n < NH; ++n){
    bf16x8 af[3];
    #pragma unroll
    for (int s = 0; s < 3; ++s){
      int ep = s*32 + kq;                       // e' in [0,96)
      int ch = n*DH + (ep >= 48 ? ep - 48 : ep);
      af[s] = *reinterpret_cast<const bf16x8*>(vtb + vt_off(prow + fr, ch));
    }
    #pragma unroll
    for (int jj = 0; jj < 3; ++jj){
      const u16* arow = ab + ((size_t)n*DH + jj*16 + fr)*96;
      #pragma unroll
      for (int s = 0; s < 3; ++s){
        bf16x8 bf = *reinterpret_cast<const bf16x8*>(arow + s*32 + kq);
        acc[n*3+jj] = __builtin_amdgcn_mfma_f32_16x16x32_bf16(af[s], bf, acc[n*3+jj], 0, 0, 0);
      }
    }
  }

  // fused LN2: per-pixel stats (pixel = row), fully intra-wave
  f32x4 s = {0.f,0.f,0.f,0.f}, s2 = {0.f,0.f,0.f,0.f};
  #pragma unroll
  for (int j = 0; j < 24; ++j){ s += acc[j]; s2 += acc[j]*acc[j]; }
  #pragma unroll
  for (int m = 1; m < 16; m <<= 1){
    #pragma unroll
    for (int r = 0; r < 4; ++r){
      s[r]  += __shfl_xor(s[r],  m);
      s2[r] += __shfl_xor(s2[r], m);
    }
  }
  f32x4 mu, rstd;
  #pragma unroll
  for (int r = 0; r < 4; ++r){
    mu[r]   = s[r] * (1.f/C_);
    rstd[r] = rsqrtf(s2[r]*(1.f/C_) - mu[r]*mu[r] + 1e-5f);
  }
  const int pbase = l0 + prow + (lane>>4)*4;
  #pragma unroll
  for (int j = 0; j < 24; ++j){
    int c = j*16 + fr;
    float wc = w2[c], bc = b2[c];
    f32x4 o;
    #pragma unroll
    for (int r = 0; r < 4; ++r)
      o[r] = (acc[j][r] - mu[r]) * rstd[r] * wc + bc;
    *reinterpret_cast<f32x4*>(out + ((size_t)bb*C_ + c)*L_ + pbase) = o;
  }
}

extern "C" void kernel_launch(void* const* d_in, const int* in_sizes, int n_in,
                              void* d_out, int out_size, void* d_ws, size_t ws_size,
                              hipStream_t stream){
  const float* x     = (const float*)d_in[0];
  const float* wq    = (const float*)d_in[1];
  const float* wk    = (const float*)d_in[2];
  const float* wv    = (const float*)d_in[3];
  const float* dwq   = (const float*)d_in[4];
  const float* dwk   = (const float*)d_in[5];
  const float* dwv   = (const float*)d_in[6];
  const float* scale = (const float*)d_in[7];
  const float* ln1w  = (const float*)d_in[8];
  const float* ln1b  = (const float*)d_in[9];
  const float* ln2w  = (const float*)d_in[10];
  const float* ln2b  = (const float*)d_in[11];
  float* out = (float*)d_out;

  char* ws = (char*)d_ws;
  u16*   qkv    = (u16*)ws;                          // [3][B][C][L] bf16  = 150,994,944 B
  u16*   xt     = (u16*)(ws + 150994944);            // [B*L][C] bf16     =  50,331,648 B
  u16*   wc     = (u16*)(ws + 201326592);            // [1152][384] bf16  =     884,736 B
  float* sumsq  = (float*)(ws + 202211328);          // [2][B*C] f32      =      12,288 B
  float* Spart  = (float*)(ws + 202223616);          // [8][32][2304] f32 =   2,359,296 B
  u16*   attn96 = (u16*)(ws + 204582912);            // [32][48][96] u16  =     294,912 B

  k_prep   <<<2752, 256, 0, stream>>>(x, ln1w, ln1b, xt, wq, wk, wv, wc);
  k_gemm   <<<2304, 512, 0, stream>>>(wc, xt, qkv);
  k_dwconv <<<3*B_*C_, 256, 0, stream>>>(qkv, dwq, dwk, dwv, sumsq);
  k_qk     <<<SPLIT*B_*NH, 512, 0, stream>>>(qkv, Spart);
  k_softmax<<<B_*NH, 64, 0, stream>>>(Spart, sumsq, scale, attn96);
  k_av_ln2 <<<1024, 256, 0, stream>>>(qkv, attn96, ln2w, ln2b, out);
}

// Round 14
// 260.125 us; speedup vs baseline: 1.0445x; 1.0445x over previous
//
#include <hip/hip_runtime.h>
#include <hip/hip_bf16.h>
#include <stdint.h>

#define B_ 4
#define C_ 384
#define H_ 128
#define W_ 128
#define L_ (H_*W_)      // 16384
#define NH 8
#define DH 48           // C_/NH
#define SPLIT 8

typedef __attribute__((ext_vector_type(8))) short bf16x8;
typedef __attribute__((ext_vector_type(4))) float f32x4;
typedef unsigned short u16;
typedef unsigned int u32;

__device__ __forceinline__ float bf2f(u16 v){
  union { float f; u32 u; } x; x.u = ((u32)v) << 16; return x.f;
}
__device__ __forceinline__ u16 f2bf(float f){
  __hip_bfloat16 h = __float2bfloat16(f);
  return *reinterpret_cast<u16*>(&h);
}

#define GLOAD_LDS16(g, l) \
  __builtin_amdgcn_global_load_lds((const __attribute__((address_space(1))) u32*)(g), \
                                   (__attribute__((address_space(3))) u32*)(l), 16, 0, 0)

// ---------------- K1: fused prep: LN1 (blocks 0..1023) + weight convert (1024..2751) ----------------
__global__ __launch_bounds__(256) void k_prep(const float* __restrict__ x,
                                              const float* __restrict__ w,
                                              const float* __restrict__ b,
                                              u16* __restrict__ xt,
                                              const float* __restrict__ wq,
                                              const float* __restrict__ wk,
                                              const float* __restrict__ wv,
                                              u16* __restrict__ wc){
  if ((int)blockIdx.x >= 1024){
    int i = ((int)blockIdx.x - 1024) * 256 + threadIdx.x;
    if (i < 3*C_*C_){
      int m = i / C_;
      int c = i - m*C_;
      const float* src = (m < C_) ? wq : (m < 2*C_) ? wk : wv;
      int mm = (m >= 2*C_) ? m - 2*C_ : (m >= C_) ? m - C_ : m;
      wc[i] = f2bf(src[mm*C_ + c]);
    }
    return;
  }
  const int tid = threadIdx.x;
  const int bb = blockIdx.x >> 8;          // 256 blocks per batch
  const int l0 = (blockIdx.x & 255) << 6;  // 64-pixel tile
  const int pg = tid >> 4;                 // 0..15, pixels pg*4..pg*4+3
  const int cg = tid & 15;                 // 0..15, channels cg*24..cg*24+23
  const int c0 = cg * 24;
  const float* xp = x + (size_t)bb*C_*L_ + (size_t)c0*L_ + l0 + pg*4;

  f32x4 vals[24];
  #pragma unroll
  for (int ci = 0; ci < 24; ++ci)
    vals[ci] = *reinterpret_cast<const f32x4*>(xp + (size_t)ci*L_);

  f32x4 s = {0.f,0.f,0.f,0.f}, s2 = {0.f,0.f,0.f,0.f};
  #pragma unroll
  for (int ci = 0; ci < 24; ++ci){ s += vals[ci]; s2 += vals[ci]*vals[ci]; }
  #pragma unroll
  for (int m = 1; m < 16; m <<= 1){
    #pragma unroll
    for (int r = 0; r < 4; ++r){
      s[r]  += __shfl_xor(s[r],  m);
      s2[r] += __shfl_xor(s2[r], m);
    }
  }
  f32x4 mu, rstd;
  #pragma unroll
  for (int r = 0; r < 4; ++r){
    mu[r]   = s[r] * (1.f/C_);
    rstd[r] = rsqrtf(s2[r]*(1.f/C_) - mu[r]*mu[r] + 1e-5f);
  }

  u16* dst = xt + ((size_t)bb*L_ + l0 + pg*4)*C_ + c0;
  #pragma unroll
  for (int j = 0; j < 3; ++j){
    f32x4 w0 = *reinterpret_cast<const f32x4*>(w + c0 + j*8);
    f32x4 w1 = *reinterpret_cast<const f32x4*>(w + c0 + j*8 + 4);
    f32x4 b0 = *reinterpret_cast<const f32x4*>(b + c0 + j*8);
    f32x4 b1 = *reinterpret_cast<const f32x4*>(b + c0 + j*8 + 4);
    #pragma unroll
    for (int pp = 0; pp < 4; ++pp){
      uint4 pk;
      u16* tp = reinterpret_cast<u16*>(&pk);
      #pragma unroll
      for (int e = 0; e < 4; ++e)
        tp[e]   = f2bf((vals[j*8+e][pp]   - mu[pp]) * rstd[pp] * w0[e] + b0[e]);
      #pragma unroll
      for (int e = 0; e < 4; ++e)
        tp[4+e] = f2bf((vals[j*8+4+e][pp] - mu[pp]) * rstd[pp] * w1[e] + b1[e]);
      *reinterpret_cast<uint4*>(dst + (size_t)pp*C_ + j*8) = pk;
    }
  }
}

// ---------------- K2: GEMM qkv = Wc[1152x384] * xt^T -> [3][B][C][L] bf16 ----------------
// PROVEN R8 structure (reproduced 5x at 83-84 us): 128x256 tile, 512 thr / 8 waves,
// triple-buffered LDS, counted s_waitcnt vmcnt(3), both-sides swizzle, XCD remap.
// Do NOT: register A-loads (R11, -73%), BK=64 phase-split (R13, -14%), split grids (R9).
#define SLOTA (128*32)   // u16 elements per A slot (8 KB)
#define SLOTB (256*32)   // u16 elements per B slot (16 KB)
__global__ __launch_bounds__(512) void k_gemm(const u16* __restrict__ Wc,
                                              const u16* __restrict__ Xt,
                                              u16* __restrict__ qkv){
  __shared__ u16 As[3*SLOTA];   // 24 KB
  __shared__ u16 Bs[3*SLOTB];   // 48 KB
  const int tid = threadIdx.x;
  const int wg = (int)blockIdx.x;
  const int lin = (wg & 7) * 288 + (wg >> 3);
  const int bm = lin % 9;
  const int bn = lin / 9;
  const int m0 = bm * 128;
  const int n0 = bn * 256;
  const int w = tid >> 6, lane = tid & 63;
  const int wm = (w >> 2) * 64, wn = (w & 3) * 64;
  const int fr = lane & 15, kqi = lane >> 4;
  const int sslot = kqi ^ ((fr >> 1) & 3);   // swizzled 16B slot (row&7 == fr&7)

  f32x4 acc[4][4] = {};

#define STAGE(slot, k0) do { \
    { int rowA_ = tid >> 2, qA_ = tid & 3; \
      int qsA_ = qA_ ^ ((rowA_ >> 1) & 3); \
      GLOAD_LDS16(Wc + (size_t)(m0+rowA_)*384 + (k0) + qsA_*8, As + (slot)*SLOTA + tid*8); } \
    _Pragma("unroll") \
    for (int i_ = 0; i_ < 2; ++i_){ \
      int idx_ = i_*512 + tid; \
      int row_ = idx_ >> 2, q_ = idx_ & 3; \
      int qs_ = q_ ^ ((row_ >> 1) & 3); \
      GLOAD_LDS16(Xt + (size_t)(n0+row_)*384 + (k0) + qs_*8, Bs + (slot)*SLOTB + idx_*8); \
    } } while(0)

  STAGE(0, 0);
  STAGE(1, 32);

  #pragma unroll
  for (int it = 0; it < 12; ++it){
    const int cur = it % 3;
    __builtin_amdgcn_sched_barrier(0);
    if (it < 11) asm volatile("s_waitcnt vmcnt(3)" ::: "memory");
    else         asm volatile("s_waitcnt vmcnt(0)" ::: "memory");
    __builtin_amdgcn_sched_barrier(0);
    __builtin_amdgcn_s_barrier();
    __builtin_amdgcn_sched_barrier(0);
    if (it + 2 < 12) STAGE((it+2)%3, (it+2)*32);

    const u16* Ab = As + cur*SLOTA;
    const u16* Bb = Bs + cur*SLOTB;
    bf16x8 af[4], bfm[4];
    #pragma unroll
    for (int i = 0; i < 4; ++i)
      af[i] = *reinterpret_cast<const bf16x8*>(Ab + (wm + i*16 + fr)*32 + sslot*8);
    #pragma unroll
    for (int j = 0; j < 4; ++j)
      bfm[j] = *reinterpret_cast<const bf16x8*>(Bb + (wn + j*16 + fr)*32 + sslot*8);
    #pragma unroll
    for (int i = 0; i < 4; ++i)
      #pragma unroll
      for (int j = 0; j < 4; ++j)
        acc[i][j] = __builtin_amdgcn_mfma_f32_16x16x32_bf16(af[i], bfm[j], acc[i][j], 0, 0, 0);
  }
#undef STAGE

  #pragma unroll
  for (int i = 0; i < 4; ++i){
    int mbase = m0 + wm + i*16 + (lane >> 4) * 4;
    #pragma unroll
    for (int j = 0; j < 4; ++j){
      int n = n0 + wn + j*16 + fr;
      int bb = n >> 14, l = n & (L_-1);
      #pragma unroll
      for (int r = 0; r < 4; ++r){
        int m = mbase + r;
        int proj = (m >= 2*C_) ? 2 : (m >= C_) ? 1 : 0;
        int c = m - proj*C_;
        qkv[(((size_t)proj*B_ + bb)*C_ + c)*L_ + l] = f2bf(acc[i][j][r]);
      }
    }
  }
}

// ---------------- K3: depthwise 3x3 in-place + per-channel sumsq for q,k ----------------
__global__ __launch_bounds__(256) void k_dwconv(u16* __restrict__ qkv,
                                                const float* __restrict__ dwq,
                                                const float* __restrict__ dwk,
                                                const float* __restrict__ dwv,
                                                float* __restrict__ sumsq){
  __shared__ u16 pl[128*128];
  int pid = blockIdx.x;                  // t*B*C + b*C + c
  int t = pid / (B_*C_);
  int bc = pid - t*(B_*C_);
  int c = bc % C_;
  const float* dw = ((t == 0) ? dwq : (t == 1) ? dwk : dwv) + c*9;
  u16* plane = qkv + ((size_t)t*B_*C_ + bc) * L_;
  int tid = threadIdx.x;
  #pragma unroll
  for (int i = 0; i < 8; ++i){
    int idx = i*256 + tid;
    GLOAD_LDS16(plane + idx*8, pl + idx*8);
  }
  float wgt[9];
  #pragma unroll
  for (int i = 0; i < 9; ++i) wgt[i] = dw[i];
  asm volatile("s_waitcnt vmcnt(0)" ::: "memory");
  __syncthreads();

  const int tx = tid & 15;           // tile col: pixels tx*8..tx*8+7
  const int ty = tid >> 4;           // tile row: rows ty*8..ty*8+7
  const int lane = tid & 63;
  const int y0 = ty*8;

  float rv[3][8], rl[3], rr_[3];
  float ss = 0.f;

  #pragma unroll
  for (int i = 0; i < 10; ++i){
    const int sl = i % 3;
    int r = y0 - 1 + i;
    int rc = (r < 0) ? 0 : (r > 127 ? 127 : r);
    uint4 pk = *reinterpret_cast<const uint4*>(pl + rc*128 + tx*8);
    const u16* e = reinterpret_cast<const u16*>(&pk);
    bool oob = (r < 0) || (r > 127);
    #pragma unroll
    for (int k = 0; k < 8; ++k)
      rv[sl][k] = oob ? 0.f : bf2f(e[k]);
    float lft = __shfl(rv[sl][7], lane - 1);
    float rgt = __shfl(rv[sl][0], lane + 1);
    rl[sl]  = (tx == 0)  ? 0.f : lft;
    rr_[sl] = (tx == 15) ? 0.f : rgt;

    if (i >= 2){
      const int sa = (i-2) % 3, sb = (i-1) % 3, sc = i % 3;
      const int y = i - 2;
      float o[8];
      #pragma unroll
      for (int xx = 0; xx < 8; ++xx){
        float am1 = (xx == 0) ? rl[sa]  : rv[sa][xx-1];
        float ap1 = (xx == 7) ? rr_[sa] : rv[sa][xx+1];
        float bm1 = (xx == 0) ? rl[sb]  : rv[sb][xx-1];
        float bp1 = (xx == 7) ? rr_[sb] : rv[sb][xx+1];
        float cm1 = (xx == 0) ? rl[sc]  : rv[sc][xx-1];
        float cp1 = (xx == 7) ? rr_[sc] : rv[sc][xx+1];
        float a = wgt[0]*am1 + wgt[1]*rv[sa][xx] + wgt[2]*ap1
                + wgt[3]*bm1 + wgt[4]*rv[sb][xx] + wgt[5]*bp1
                + wgt[6]*cm1 + wgt[7]*rv[sc][xx] + wgt[8]*cp1;
        o[xx] = a;
        ss += a * a;
      }
      uint4 st;
      u16* sp = reinterpret_cast<u16*>(&st);
      #pragma unroll
      for (int xx = 0; xx < 8; ++xx) sp[xx] = f2bf(o[xx]);
      *reinterpret_cast<uint4*>(plane + (y0 + y)*128 + tx*8) = st;
    }
  }

  if (t < 2){
    #pragma unroll
    for (int off = 32; off > 0; off >>= 1) ss += __shfl_down(ss, off);
    __shared__ float red[4];
    if ((tid & 63) == 0) red[tid >> 6] = ss;
    __syncthreads();
    if (tid == 0) sumsq[t*(B_*C_) + bc] = red[0] + red[1] + red[2] + red[3];
  }
}

// ---------------- K4: attention logits (split-K over L), S_part[s][b][n][48][48] ----------------
// SPLIT=8, 512 threads / 8 waves per block; per-wave LDS slice + parallel 8-way reduce.
__global__ __launch_bounds__(512) void k_qk(const u16* __restrict__ qkv,
                                            float* __restrict__ Spart){
  int gid = blockIdx.x;                 // (s*B + b)*NH + n
  int s = gid / (B_*NH);
  int bn = gid - s*(B_*NH);
  int b = bn / NH, n = bn - b*NH;
  const u16* qb = qkv + ((size_t)b*C_ + n*DH) * L_;
  const u16* kb = qkv + ((size_t)B_*C_ + (size_t)b*C_ + n*DH) * L_;
  int tid = threadIdx.x, w = tid >> 6, lane = tid & 63;
  int fr = lane & 15, kq = (lane >> 4) * 8;
  int l0 = s * (L_/SPLIT) + w * (L_/SPLIT/8);     // 2048/block, 256/wave
  f32x4 acc[3][3] = {};
  #pragma unroll
  for (int kk = 0; kk < (L_/SPLIT/8); kk += 32){
    int koff = l0 + kk + kq;
    bf16x8 af[3], bfm[3];
    #pragma unroll
    for (int i = 0; i < 3; ++i) af[i]  = *reinterpret_cast<const bf16x8*>(qb + (size_t)(i*16+fr)*L_ + koff);
    #pragma unroll
    for (int j = 0; j < 3; ++j) bfm[j] = *reinterpret_cast<const bf16x8*>(kb + (size_t)(j*16+fr)*L_ + koff);
    #pragma unroll
    for (int i = 0; i < 3; ++i)
      #pragma unroll
      for (int j = 0; j < 3; ++j)
        acc[i][j] = __builtin_amdgcn_mfma_f32_16x16x32_bf16(af[i], bfm[j], acc[i][j], 0, 0, 0);
  }
  __shared__ float red[8*2304];        // 73.7 KB, one 48x48 slice per wave
  float* rw = red + w*2304;
  #pragma unroll
  for (int i = 0; i < 3; ++i)
    #pragma unroll
    for (int j = 0; j < 3; ++j)
      #pragma unroll
      for (int r = 0; r < 4; ++r){
        int row = i*16 + (lane >> 4)*4 + r;
        int col = j*16 + fr;
        rw[row*48 + col] = acc[i][j][r];
      }
  __syncthreads();
  float* dst = Spart + ((size_t)gid) * 2304;
  for (int idx = tid; idx < 2304; idx += 512){
    float a = 0.f;
    #pragma unroll
    for (int ww = 0; ww < 8; ++ww) a += red[ww*2304 + idx];
    dst[idx] = a;
  }
}

// ---------------- K5: reduce split-K, fold L2 norms + scale, softmax -> bf16 hi|lo [d][96] ----------------
__global__ void k_softmax(const float* __restrict__ Spart,
                          const float* __restrict__ sumsq,
                          const float* __restrict__ scale,
                          u16* __restrict__ attn96){
  int bn = blockIdx.x;                  // b*NH + n
  int b = bn / NH, n = bn - b*NH;
  int i = threadIdx.x;
  if (i >= DH) return;
  const float* sq = sumsq + (size_t)b*C_ + n*DH;
  const float* sk = sumsq + (size_t)B_*C_ + (size_t)b*C_ + n*DH;
  float nq = fmaxf(sqrtf(sq[i]), 1e-12f);
  float sc = scale[n];
  float row[48];
  #pragma unroll
  for (int j = 0; j < DH; ++j){
    float acc = 0.f;
    #pragma unroll
    for (int s = 0; s < SPLIT; ++s)
      acc += Spart[((size_t)(s*(B_*NH) + bn))*2304 + i*48 + j];
    float nk = fmaxf(sqrtf(sk[j]), 1e-12f);
    row[j] = acc / (nq * nk) * sc;
  }
  float m = row[0];
  #pragma unroll
  for (int j = 1; j < DH; ++j) m = fmaxf(m, row[j]);
  float sum = 0.f;
  #pragma unroll
  for (int j = 0; j < DH; ++j){ row[j] = __expf(row[j] - m); sum += row[j]; }
  float inv = 1.f / sum;
  u16* dst = attn96 + ((size_t)bn)*DH*96 + i*96;     // row d=i: hi[0..48) | lo[48..96)
  #pragma unroll
  for (int j = 0; j < DH; ++j){
    float a = row[j] * inv;
    u16 hi = f2bf(a);
    float lo = a - bf2f(hi);
    dst[j]      = hi;
    dst[48 + j] = f2bf(lo);
  }
}

// ---------------- K6: out = attn @ v via MFMA (hi+lo split-K=96), fused LayerNorm ----------------
#define VT_STRIDE 784
__device__ __forceinline__ int vt_off(int p, int ch){
  return p*VT_STRIDE + ((p>>3)<<4) + 2*ch;
}
__global__ __launch_bounds__(256) void k_av_ln2(const u16* __restrict__ qkv,
                                                const u16* __restrict__ attn96,
                                                const float* __restrict__ w2,
                                                const float* __restrict__ b2,
                                                float* __restrict__ out){
  __shared__ u16 vt[(64*VT_STRIDE + 8*16)/2];     // 50304 B
  char* vtb = reinterpret_cast<char*>(vt);
  const int tid = threadIdx.x;
  const int bb = blockIdx.x >> 8;        // 256 tiles per batch
  const int l0 = (blockIdx.x & 255) << 6;
  const u16* vg = qkv + ((size_t)2*B_*C_ + (size_t)bb*C_)*L_ + l0;

  // stage v[c][l0..l0+63] -> vt[p][c] (transposed): channel-pairs, u32 writes
  #pragma unroll
  for (int it = 0; it < 6; ++it){
    int idx = it*256 + tid;            // 0..1535
    int cp = idx >> 3, g = idx & 7;    // cp: channel pair 0..191, g: pixel group
    int c = cp*2;
    uint4 p0 = *reinterpret_cast<const uint4*>(vg + (size_t)c*L_ + g*8);
    uint4 p1 = *reinterpret_cast<const uint4*>(vg + (size_t)(c+1)*L_ + g*8);
    const u16* e0 = reinterpret_cast<const u16*>(&p0);
    const u16* e1 = reinterpret_cast<const u16*>(&p1);
    #pragma unroll
    for (int j = 0; j < 8; ++j){
      int p = g*8 + j;
      u32 packed = ((u32)e0[j]) | (((u32)e1[j]) << 16);
      *reinterpret_cast<u32*>(vtb + vt_off(p, c)) = packed;
    }
  }
  __syncthreads();

  const int w = tid >> 6, lane = tid & 63;
  const int fr = lane & 15, kq = (lane >> 4) * 8;
  const int prow = w*16;
  f32x4 acc[24];
  #pragma unroll
  for (int j = 0; j < 24; ++j) acc[j] = (f32x4){0.f,0.f,0.f,0.f};

  const u16* ab = attn96 + ((size_t)bb*NH)*DH*96;
  #pragma unroll
  for (int n = 0; n < NH; ++n){
    bf16x8 af[3];
    #pragma unroll
    for (int s = 0; s < 3; ++s){
      int ep = s*32 + kq;                       // e' in [0,96)
      int ch = n*DH + (ep >= 48 ? ep - 48 : ep);
      af[s] = *reinterpret_cast<const bf16x8*>(vtb + vt_off(prow + fr, ch));
    }
    #pragma unroll
    for (int jj = 0; jj < 3; ++jj){
      const u16* arow = ab + ((size_t)n*DH + jj*16 + fr)*96;
      #pragma unroll
      for (int s = 0; s < 3; ++s){
        bf16x8 bf = *reinterpret_cast<const bf16x8*>(arow + s*32 + kq);
        acc[n*3+jj] = __builtin_amdgcn_mfma_f32_16x16x32_bf16(af[s], bf, acc[n*3+jj], 0, 0, 0);
      }
    }
  }

  // fused LN2: per-pixel stats (pixel = row), fully intra-wave
  f32x4 s = {0.f,0.f,0.f,0.f}, s2 = {0.f,0.f,0.f,0.f};
  #pragma unroll
  for (int j = 0; j < 24; ++j){ s += acc[j]; s2 += acc[j]*acc[j]; }
  #pragma unroll
  for (int m = 1; m < 16; m <<= 1){
    #pragma unroll
    for (int r = 0; r < 4; ++r){
      s[r]  += __shfl_xor(s[r],  m);
      s2[r] += __shfl_xor(s2[r], m);
    }
  }
  f32x4 mu, rstd;
  #pragma unroll
  for (int r = 0; r < 4; ++r){
    mu[r]   = s[r] * (1.f/C_);
    rstd[r] = rsqrtf(s2[r]*(1.f/C_) - mu[r]*mu[r] + 1e-5f);
  }
  const int pbase = l0 + prow + (lane>>4)*4;
  #pragma unroll
  for (int j = 0; j < 24; ++j){
    int c = j*16 + fr;
    float wc = w2[c], bc = b2[c];
    f32x4 o;
    #pragma unroll
    for (int r = 0; r < 4; ++r)
      o[r] = (acc[j][r] - mu[r]) * rstd[r] * wc + bc;
    *reinterpret_cast<f32x4*>(out + ((size_t)bb*C_ + c)*L_ + pbase) = o;
  }
}

extern "C" void kernel_launch(void* const* d_in, const int* in_sizes, int n_in,
                              void* d_out, int out_size, void* d_ws, size_t ws_size,
                              hipStream_t stream){
  const float* x     = (const float*)d_in[0];
  const float* wq    = (const float*)d_in[1];
  const float* wk    = (const float*)d_in[2];
  const float* wv    = (const float*)d_in[3];
  const float* dwq   = (const float*)d_in[4];
  const float* dwk   = (const float*)d_in[5];
  const float* dwv   = (const float*)d_in[6];
  const float* scale = (const float*)d_in[7];
  const float* ln1w  = (const float*)d_in[8];
  const float* ln1b  = (const float*)d_in[9];
  const float* ln2w  = (const float*)d_in[10];
  const float* ln2b  = (const float*)d_in[11];
  float* out = (float*)d_out;

  char* ws = (char*)d_ws;
  u16*   qkv    = (u16*)ws;                          // [3][B][C][L] bf16  = 150,994,944 B
  u16*   xt     = (u16*)(ws + 150994944);            // [B*L][C] bf16     =  50,331,648 B
  u16*   wc     = (u16*)(ws + 201326592);            // [1152][384] bf16  =     884,736 B
  float* sumsq  = (float*)(ws + 202211328);          // [2][B*C] f32      =      12,288 B
  float* Spart  = (float*)(ws + 202223616);          // [8][32][2304] f32 =   2,359,296 B
  u16*   attn96 = (u16*)(ws + 204582912);            // [32][48][96] u16  =     294,912 B

  k_prep   <<<2752, 256, 0, stream>>>(x, ln1w, ln1b, xt, wq, wk, wv, wc);
  k_gemm   <<<2304, 512, 0, stream>>>(wc, xt, qkv);
  k_dwconv <<<3*B_*C_, 256, 0, stream>>>(qkv, dwq, dwk, dwv, sumsq);
  k_qk     <<<SPLIT*B_*NH, 512, 0, stream>>>(qkv, Spart);
  k_softmax<<<B_*NH, 64, 0, stream>>>(Spart, sumsq, scale, attn96);
  k_av_ln2 <<<1024, 256, 0, stream>>>(qkv, attn96, ln2w, ln2b, out);
}